// Round 6
// baseline (169.797 us; speedup 1.0000x reference)
//
#include <hip/hip_runtime.h>

#define N_NODES 100000
#define N_EDGES 1600000
#define HID 32
#define BN_EPS 1e-5f

#define EPB   4096                 // edges per bin block
#define NBLK  391                  // ceil(N_EDGES / EPB)
#define BSZ   512                  // dst nodes per bucket
#define NBUCK 196                  // ceil(N_NODES / BSZ)
#define SRC_MASK 0x1FFFFu
#define GSPL  8                    // run-dimension split per bucket
#define RPB   ((NBLK + GSPL - 1) / GSPL)   // 49 runs per split-block

// ============================ binned path ============================

// Each block bins its contiguous 4096-edge slice by dst-bucket entirely in LDS,
// then writes the slice back coalesced (ordered by bucket) + run metadata.
// NO scattered global writes, NO global atomics.
__global__ void bin_kernel(const int* __restrict__ src, const int* __restrict__ dst,
                           unsigned* __restrict__ bbuf, int* __restrict__ blen,
                           int* __restrict__ boffs) {
    __shared__ int hist[NBUCK], offs[NBUCK], curs[NBUCK];
    __shared__ int sc[256];
    __shared__ unsigned stage[EPB];
    int tid = threadIdx.x, blk = blockIdx.x;
    int e0 = blk * EPB;
    int cnt = N_EDGES - e0; if (cnt > EPB) cnt = EPB;

    unsigned pk[EPB / 256];
    int bk[EPB / 256];
#pragma unroll
    for (int i = 0; i < EPB / 256; ++i) {
        int j = tid + i * 256;
        if (j < cnt) {
            int e = e0 + j;
            int s = src[e], d = dst[e];
            bk[i] = d >> 9;
            pk[i] = ((unsigned)(d & (BSZ - 1)) << 17) | (unsigned)s;
        } else bk[i] = -1;
    }
    for (int j = tid; j < NBUCK; j += 256) hist[j] = 0;
    __syncthreads();
#pragma unroll
    for (int i = 0; i < EPB / 256; ++i)
        if (bk[i] >= 0) atomicAdd(&hist[bk[i]], 1);
    __syncthreads();
    // Hillis-Steele inclusive scan over 256 (NBUCK padded with zeros)
    int h = (tid < NBUCK) ? hist[tid] : 0;
    sc[tid] = h;
    __syncthreads();
    for (int off = 1; off < 256; off <<= 1) {
        int v = (tid >= off) ? sc[tid - off] : 0;
        __syncthreads();
        sc[tid] += v;
        __syncthreads();
    }
    if (tid < NBUCK) { offs[tid] = sc[tid] - h; curs[tid] = sc[tid] - h; }
    __syncthreads();
#pragma unroll
    for (int i = 0; i < EPB / 256; ++i)
        if (bk[i] >= 0) {
            int p = atomicAdd(&curs[bk[i]], 1);
            stage[p] = pk[i];
        }
    __syncthreads();
    for (int j = tid; j < cnt; j += 256) bbuf[e0 + j] = stage[j];   // coalesced
    for (int j = tid; j < NBUCK; j += 256) {
        blen[j * NBLK + blk]  = hist[j];
        boffs[j * NBLK + blk] = e0 + offs[j];
    }
}

// (bucket, split) per block: LDS local-degree histogram over this split's runs,
// wave-cooperative run walk; coalesced global atomic merge into cnt.
__global__ void deg_kernel(const unsigned* __restrict__ bbuf, const int* __restrict__ blen,
                           const int* __restrict__ boffs, int* __restrict__ cnt) {
    __shared__ int hist[BSZ];
    int tid = threadIdx.x;
    int b = blockIdx.x >> 3;         // bucket
    int g = blockIdx.x & 7;          // split
    for (int j = tid; j < BSZ; j += 256) hist[j] = 0;
    __syncthreads();
    int wave = tid >> 6, lane = tid & 63;
    int r0 = g * RPB;
    int r1 = r0 + RPB; if (r1 > NBLK) r1 = NBLK;
    for (int r = r0 + wave; r < r1; r += 4) {
        int len = blen[b * NBLK + r];
        int off = boffs[b * NBLK + r];
        for (int k = lane; k < len; k += 64)
            atomicAdd(&hist[bbuf[off + k] >> 17], 1);
    }
    __syncthreads();
    int base = b << 9;
    for (int l = tid; l < BSZ; l += 256) {
        int h = hist[l];
        if (h && base + l < N_NODES) atomicAdd(&cnt[base + l], h);   // coalesced
    }
}

// per node: xd[n] = (x_n * rd_n, rd_n); S4 initialized with the self-loop term xd[n]
__global__ void xd_kernel(const float* __restrict__ x, const int* __restrict__ cnt,
                          float4* __restrict__ xd, float4* __restrict__ S4) {
    int n = blockIdx.x * blockDim.x + threadIdx.x;
    if (n >= N_NODES) return;
    float rd = rsqrtf(1.0f + (float)cnt[n]);
    float4 v = make_float4(x[3 * n] * rd, x[3 * n + 1] * rd, x[3 * n + 2] * rd, rd);
    xd[n] = v;
    S4[n] = v;   // self contribution
}

// (bucket, split) per block: partial S in LDS via wave-cooperative run walk,
// coalesced global atomic merge into S4.xyz.
__global__ void accum_kernel(const unsigned* __restrict__ bbuf, const int* __restrict__ blen,
                             const int* __restrict__ boffs, const float4* __restrict__ xd,
                             float4* __restrict__ S4) {
    __shared__ float S[BSZ * 3];
    int tid = threadIdx.x;
    int b = blockIdx.x >> 3;
    int g = blockIdx.x & 7;
    for (int j = tid; j < BSZ * 3; j += 256) S[j] = 0.f;
    __syncthreads();
    int wave = tid >> 6, lane = tid & 63;
    int r0 = g * RPB;
    int r1 = r0 + RPB; if (r1 > NBLK) r1 = NBLK;
    for (int r = r0 + wave; r < r1; r += 4) {
        int len = blen[b * NBLK + r];
        int off = boffs[b * NBLK + r];
        for (int k = lane; k < len; k += 64) {
            unsigned p = bbuf[off + k];
            float4 v = xd[p & SRC_MASK];
            int l3 = (int)(p >> 17) * 3;
            atomicAdd(&S[l3 + 0], v.x);
            atomicAdd(&S[l3 + 1], v.y);
            atomicAdd(&S[l3 + 2], v.z);
        }
    }
    __syncthreads();
    int base = b << 9;
    for (int l = tid; l < BSZ; l += 256) {
        int n = base + l;
        if (n < N_NODES) {
            float sx = S[l * 3 + 0], sy = S[l * 3 + 1], sz = S[l * 3 + 2];
            if (sx != 0.f || sy != 0.f || sz != 0.f) {
                float* p = (float*)&S4[n];
                atomicAdd(p + 0, sx);
                atomicAdd(p + 1, sy);
                atomicAdd(p + 2, sz);       // coalesced (contiguous nodes)
            }
        }
    }
}

// 9-scalar BN sufficient statistics over a = rd*S
__global__ void stats_kernel(const float4* __restrict__ S4, float* __restrict__ stats) {
    __shared__ float ls[4][9];
    int tid = threadIdx.x;
    int n = blockIdx.x * blockDim.x + tid;
    float st[9];
#pragma unroll
    for (int q = 0; q < 9; ++q) st[q] = 0.f;
    if (n < N_NODES) {
        float4 s = S4[n];
        float ax = s.w * s.x, ay = s.w * s.y, az = s.w * s.z;
        st[0] = ax; st[1] = ay; st[2] = az;
        st[3] = ax * ax; st[4] = ax * ay; st[5] = ax * az;
        st[6] = ay * ay; st[7] = ay * az; st[8] = az * az;
    }
    for (int m = 1; m < 64; m <<= 1)
#pragma unroll
        for (int q = 0; q < 9; ++q) st[q] += __shfl_xor(st[q], m);
    int wave = tid >> 6;
    if ((tid & 63) == 0)
#pragma unroll
        for (int q = 0; q < 9; ++q) ls[wave][q] = st[q];
    __syncthreads();
    if (tid < 9) {
        float s = ls[0][tid] + ls[1][tid] + ls[2][tid] + ls[3][tid];
        atomicAdd(&stats[tid], s);
    }
}

// fold BN scale/shift into W and b: cbuf = {W0*sc, W1*sc, W2*sc, b*sc + sh}
__global__ void finalize_kernel(const float* __restrict__ stats, const float* __restrict__ W,
                                const float* __restrict__ b, const float* __restrict__ gamma,
                                const float* __restrict__ beta, float* __restrict__ cbuf) {
    int c = threadIdx.x;
    if (c >= HID) return;
    float m1x = stats[0], m1y = stats[1], m1z = stats[2];
    float Mxx = stats[3], Mxy = stats[4], Mxz = stats[5];
    float Myy = stats[6], Myz = stats[7], Mzz = stats[8];
    float w0 = W[c], w1 = W[HID + c], w2 = W[2 * HID + c];
    const float invn = 1.0f / (float)N_NODES;
    float m1w = m1x * w0 + m1y * w1 + m1z * w2;
    float mean = m1w * invn + b[c];
    float quad = w0 * w0 * Mxx + w1 * w1 * Myy + w2 * w2 * Mzz
               + 2.f * (w0 * w1 * Mxy + w0 * w2 * Mxz + w1 * w2 * Myz);
    float ex2 = quad * invn + 2.f * b[c] * m1w * invn + b[c] * b[c];
    float var = ex2 - mean * mean;
    float inv = rsqrtf(var + BN_EPS);
    float sc = gamma[c] * inv;
    float sh = beta[c] - mean * sc;
    cbuf[c] = w0 * sc;
    cbuf[HID + c] = w1 * sc;
    cbuf[2 * HID + c] = w2 * sc;
    cbuf[3 * HID + c] = b[c] * sc + sh;
}

// streaming output: y = rd*(S . Wsc_c) + shift_c, PReLU
__global__ void final_out_kernel(const float4* __restrict__ S4, const float* __restrict__ cbuf,
                                 const float* __restrict__ prelu, float* __restrict__ out) {
    int t = blockIdx.x * blockDim.x + threadIdx.x;
    if (t >= N_NODES * HID) return;
    int n = t >> 5, c = t & 31;
    float4 s = S4[n];
    float y = s.w * (s.x * cbuf[c] + s.y * cbuf[HID + c] + s.z * cbuf[2 * HID + c])
            + cbuf[3 * HID + c];
    float a = prelu[0];
    out[t] = y >= 0.f ? y : a * y;
}

// ============================ fallback (round-4) path ============================

__global__ void fb_count_kernel(const int* __restrict__ dst, int* __restrict__ cnt) {
    int e = blockIdx.x * blockDim.x + threadIdx.x;
    if (e < N_EDGES) atomicAdd(&cnt[dst[e]], 1);
}

__global__ void fb_scatter_kernel(const int* __restrict__ src, const int* __restrict__ dst,
                                  const float4* __restrict__ xd, float4* __restrict__ S4) {
    int e = blockIdx.x * blockDim.x + threadIdx.x;
    if (e >= N_EDGES) return;
    int s = src[e], d = dst[e];
    float4 v = xd[s];
    float* p = (float*)&S4[d];
    atomicAdd(p + 0, v.x);
    atomicAdd(p + 1, v.y);
    atomicAdd(p + 2, v.z);
}

// ============================ launch ============================

extern "C" void kernel_launch(void* const* d_in, const int* in_sizes, int n_in,
                              void* d_out, int out_size, void* d_ws, size_t ws_size,
                              hipStream_t stream) {
    const float* x     = (const float*)d_in[0];
    const int*   ei    = (const int*)d_in[1];   // [2, E]: src row then dst row
    const float* W     = (const float*)d_in[2];
    const float* b     = (const float*)d_in[3];
    const float* gamma = (const float*)d_in[4];
    const float* beta  = (const float*)d_in[5];
    const float* prelu = (const float*)d_in[6];

    const int* src = ei;
    const int* dst = ei + N_EDGES;
    char* ws = (char*)d_ws;
    float* out = (float*)d_out;

    // ---- ws layout (binned path), total 10,619,872 B ----
    // cnt   @ 0          int[100000]        (400,000)
    // stats @ 400,000    float[16]          (64)     <- memset covers [0, 400,064)
    // cbuf  @ 400,064    float[128+pad]     (576)
    // bbuf  @ 400,640    u32[EPB*NBLK]      (6,406,144)
    // blen  @ 6,806,784  int[NBUCK*NBLK]    (306,544)
    // boffs @ 7,113,328  int[NBUCK*NBLK]    (306,544)
    // xd    @ 7,419,872  float4[100000]     (1,600,000)   (16B-aligned)
    // S4    @ 9,019,872  float4[100000]     (1,600,000)   (16B-aligned)
    const size_t NEEDED = 10619872;

    if (ws_size >= NEEDED) {
        int*      cnt   = (int*)(ws);
        float*    stats = (float*)(ws + 400000);
        float*    cbuf  = (float*)(ws + 400064);
        unsigned* bbuf  = (unsigned*)(ws + 400640);
        int*      blen  = (int*)(ws + 6806784);
        int*      boffs = (int*)(ws + 7113328);
        float4*   xd    = (float4*)(ws + 7419872);
        float4*   S4    = (float4*)(ws + 9019872);

        hipMemsetAsync(ws, 0, 400064, stream);
        bin_kernel<<<NBLK, 256, 0, stream>>>(src, dst, bbuf, blen, boffs);
        deg_kernel<<<NBUCK * GSPL, 256, 0, stream>>>(bbuf, blen, boffs, cnt);
        xd_kernel<<<(N_NODES + 255) / 256, 256, 0, stream>>>(x, cnt, xd, S4);
        accum_kernel<<<NBUCK * GSPL, 256, 0, stream>>>(bbuf, blen, boffs, xd, S4);
        stats_kernel<<<(N_NODES + 255) / 256, 256, 0, stream>>>(S4, stats);
        finalize_kernel<<<1, 64, 0, stream>>>(stats, W, b, gamma, beta, cbuf);
        final_out_kernel<<<(N_NODES * HID + 255) / 256, 256, 0, stream>>>(S4, cbuf, prelu, out);
    } else {
        // fallback: round-4 direct-atomic path (ws need ~3.6 MB)
        int*    cnt   = (int*)(ws);
        float*  stats = (float*)(ws + 400000);
        float*  cbuf  = (float*)(ws + 400064);
        float4* xd    = (float4*)(ws + 400640);
        float4* S4    = (float4*)(ws + 2000640);

        hipMemsetAsync(ws, 0, 400064, stream);
        fb_count_kernel<<<(N_EDGES + 255) / 256, 256, 0, stream>>>(dst, cnt);
        xd_kernel<<<(N_NODES + 255) / 256, 256, 0, stream>>>(x, cnt, xd, S4);
        fb_scatter_kernel<<<(N_EDGES + 255) / 256, 256, 0, stream>>>(src, dst, xd, S4);
        stats_kernel<<<(N_NODES + 255) / 256, 256, 0, stream>>>(S4, stats);
        finalize_kernel<<<1, 64, 0, stream>>>(stats, W, b, gamma, beta, cbuf);
        final_out_kernel<<<(N_NODES * HID + 255) / 256, 256, 0, stream>>>(S4, cbuf, prelu, out);
    }
}

// Round 7
// 147.523 us; speedup vs baseline: 1.1510x; 1.1510x over previous
//
#include <hip/hip_runtime.h>

#define N_NODES 100000
#define N_EDGES 1600000
#define HID 32
#define BN_EPS 1e-5f

#define EPB   4096                 // edges per bin slice
#define NBLK  391                  // ceil(N_EDGES / EPB)
#define BSZ   512                  // dst nodes per bucket
#define NBUCK 196                  // ceil(N_NODES / BSZ)
#define SRC_MASK 0x1FFFFu

// ============================ main path ============================

// Slice-local LDS bucket sort: staged (slice-ordered by bucket, coalesced writes)
// + per-(bucket, slice) run lengths / source offsets. No global atomics.
__global__ void bin_kernel(const int* __restrict__ src, const int* __restrict__ dst,
                           unsigned* __restrict__ staged, int* __restrict__ blen,
                           int* __restrict__ boffs) {
    __shared__ int hist[NBUCK], offs[NBUCK], curs[NBUCK];
    __shared__ int sc[256];
    __shared__ unsigned stage[EPB];
    int tid = threadIdx.x, blk = blockIdx.x;
    int e0 = blk * EPB;
    int cnt = N_EDGES - e0; if (cnt > EPB) cnt = EPB;

    unsigned pk[8]; int bk[8];
#pragma unroll
    for (int i = 0; i < 8; ++i) {
        int j = tid + i * 512;
        if (j < cnt) {
            int e = e0 + j;
            int d = dst[e];
            bk[i] = d >> 9;
            pk[i] = ((unsigned)(d & (BSZ - 1)) << 17) | (unsigned)src[e];
        } else bk[i] = -1;
    }
    for (int j = tid; j < NBUCK; j += 512) hist[j] = 0;
    __syncthreads();
#pragma unroll
    for (int i = 0; i < 8; ++i)
        if (bk[i] >= 0) atomicAdd(&hist[bk[i]], 1);
    __syncthreads();
    int h = (tid < NBUCK) ? hist[tid] : 0;
    if (tid < 256) sc[tid] = h;
    __syncthreads();
    for (int off = 1; off < 256; off <<= 1) {
        int v = 0;
        if (tid < 256 && tid >= off) v = sc[tid - off];
        __syncthreads();
        if (tid < 256) sc[tid] += v;
        __syncthreads();
    }
    if (tid < NBUCK) { int ex = sc[tid] - h; offs[tid] = ex; curs[tid] = ex; }
    __syncthreads();
#pragma unroll
    for (int i = 0; i < 8; ++i)
        if (bk[i] >= 0) {
            int p = atomicAdd(&curs[bk[i]], 1);
            stage[p] = pk[i];
        }
    __syncthreads();
    for (int j = tid; j < cnt; j += 512) staged[e0 + j] = stage[j];    // coalesced
    for (int j = tid; j < NBUCK; j += 512) {
        blen[j * NBLK + blk]  = hist[j];
        boffs[j * NBLK + blk] = e0 + offs[j];
    }
}

// per bucket: exclusive scan of its 391 run lengths -> runoff, total
__global__ void scan1_kernel(const int* __restrict__ blen, int* __restrict__ runoff,
                             int* __restrict__ tot) {
    __shared__ int sc[512];
    int tid = threadIdx.x, b = blockIdx.x;
    int v = (tid < NBLK) ? blen[b * NBLK + tid] : 0;
    sc[tid] = v;
    __syncthreads();
    for (int off = 1; off < 512; off <<= 1) {
        int t = (tid >= off) ? sc[tid - off] : 0;
        __syncthreads();
        sc[tid] += t;
        __syncthreads();
    }
    if (tid < NBLK) runoff[b * NBLK + tid] = sc[tid] - v;
    if (tid == 511) tot[b] = sc[511];
}

// scan 196 bucket totals -> global bucket starts
__global__ void scan2_kernel(const int* __restrict__ tot, int* __restrict__ bstart) {
    __shared__ int sc[256];
    int tid = threadIdx.x;
    int v = (tid < NBUCK) ? tot[tid] : 0;
    sc[tid] = v;
    __syncthreads();
    for (int off = 1; off < 256; off <<= 1) {
        int t = (tid >= off) ? sc[tid - off] : 0;
        __syncthreads();
        sc[tid] += t;
        __syncthreads();
    }
    if (tid < NBUCK) bstart[tid] = sc[tid] - v;
    if (tid == 255) bstart[NBUCK] = sc[255];     // == N_EDGES
}

// one block OWNS one bucket: copy its runs to bucket-contiguous bbuf2 (dest lines
// assembled fully in L2), fused LDS degree hist, plain-store xd. No global atomics.
__global__ void scatter2_kernel(const unsigned* __restrict__ staged, const int* __restrict__ blen,
                                const int* __restrict__ boffs, const int* __restrict__ runoff,
                                const int* __restrict__ bstart, const float* __restrict__ x,
                                unsigned* __restrict__ bbuf2, float4* __restrict__ xd) {
    __shared__ int hist[BSZ];
    __shared__ int l_len[NBLK], l_soff[NBLK], l_doff[NBLK];
    int tid = threadIdx.x, b = blockIdx.x;
    int bs = bstart[b];
    for (int j = tid; j < BSZ; j += 1024) hist[j] = 0;
    for (int j = tid; j < NBLK; j += 1024) {
        l_len[j]  = blen[b * NBLK + j];
        l_soff[j] = boffs[b * NBLK + j];
        l_doff[j] = bs + runoff[b * NBLK + j];
    }
    __syncthreads();
    int wv = tid >> 6, lane = tid & 63;
    for (int r = wv; r < NBLK; r += 16) {
        int len = l_len[r];
        int so = l_soff[r], dof = l_doff[r];
        for (int k = lane; k < len; k += 64) {
            unsigned p = staged[so + k];
            bbuf2[dof + k] = p;
            atomicAdd(&hist[p >> 17], 1);     // LDS only
        }
    }
    __syncthreads();
    if (tid < BSZ) {
        int n = (b << 9) + tid;
        if (n < N_NODES) {
            float rd = rsqrtf(1.0f + (float)hist[tid]);
            xd[n] = make_float4(x[3 * n] * rd, x[3 * n + 1] * rd, x[3 * n + 2] * rd, rd);
        }
    }
}

// one block OWNS one bucket: fully-coalesced contiguous edge reads, xd gathers (L2),
// LDS S accumulate, PLAIN S4 store (self term included), fused 9-scalar BN stats.
__global__ void accum_kernel(const unsigned* __restrict__ bbuf2, const int* __restrict__ bstart,
                             const float4* __restrict__ xd, float4* __restrict__ S4,
                             float* __restrict__ stats) {
    __shared__ float S[BSZ * 3];
    __shared__ float ls[16][9];
    int tid = threadIdx.x, b = blockIdx.x;
    for (int j = tid; j < BSZ * 3; j += 1024) S[j] = 0.f;
    __syncthreads();
    int e0 = bstart[b], e1 = bstart[b + 1];
    for (int e = e0 + tid; e < e1; e += 1024) {
        unsigned p = bbuf2[e];
        float4 v = xd[p & SRC_MASK];
        int l3 = (int)(p >> 17) * 3;
        atomicAdd(&S[l3 + 0], v.x);
        atomicAdd(&S[l3 + 1], v.y);
        atomicAdd(&S[l3 + 2], v.z);
    }
    __syncthreads();
    float st[9];
#pragma unroll
    for (int q = 0; q < 9; ++q) st[q] = 0.f;
    if (tid < BSZ) {
        int n = (b << 9) + tid;
        if (n < N_NODES) {
            float4 self = xd[n];
            float sx = S[tid * 3 + 0] + self.x;
            float sy = S[tid * 3 + 1] + self.y;
            float sz = S[tid * 3 + 2] + self.z;
            S4[n] = make_float4(sx, sy, sz, self.w);      // plain coalesced store
            float ax = self.w * sx, ay = self.w * sy, az = self.w * sz;
            st[0] = ax; st[1] = ay; st[2] = az;
            st[3] = ax * ax; st[4] = ax * ay; st[5] = ax * az;
            st[6] = ay * ay; st[7] = ay * az; st[8] = az * az;
        }
    }
    for (int m = 1; m < 64; m <<= 1)
#pragma unroll
        for (int q = 0; q < 9; ++q) st[q] += __shfl_xor(st[q], m);
    int wv = tid >> 6;
    if ((tid & 63) == 0)
#pragma unroll
        for (int q = 0; q < 9; ++q) ls[wv][q] = st[q];
    __syncthreads();
    if (tid < 9) {
        float s = 0.f;
#pragma unroll
        for (int w = 0; w < 16; ++w) s += ls[w][tid];
        atomicAdd(&stats[tid], s);               // 9 atomics per block
    }
}

// fused BN-fold + streaming output: each block derives cbuf from the 9 stats in LDS
__global__ void final_out_kernel(const float4* __restrict__ S4, const float* __restrict__ stats,
                                 const float* __restrict__ W, const float* __restrict__ bb,
                                 const float* __restrict__ gamma, const float* __restrict__ beta,
                                 const float* __restrict__ prelu, float* __restrict__ out) {
    __shared__ float cb[4 * HID];
    int tid = threadIdx.x;
    if (tid < HID) {
        int c = tid;
        float m1x = stats[0], m1y = stats[1], m1z = stats[2];
        float Mxx = stats[3], Mxy = stats[4], Mxz = stats[5];
        float Myy = stats[6], Myz = stats[7], Mzz = stats[8];
        float w0 = W[c], w1 = W[HID + c], w2 = W[2 * HID + c];
        const float invn = 1.0f / (float)N_NODES;
        float m1w = m1x * w0 + m1y * w1 + m1z * w2;
        float mean = m1w * invn + bb[c];
        float quad = w0 * w0 * Mxx + w1 * w1 * Myy + w2 * w2 * Mzz
                   + 2.f * (w0 * w1 * Mxy + w0 * w2 * Mxz + w1 * w2 * Myz);
        float ex2 = quad * invn + 2.f * bb[c] * m1w * invn + bb[c] * bb[c];
        float var = ex2 - mean * mean;
        float sc = gamma[c] * rsqrtf(var + BN_EPS);
        cb[c] = w0 * sc;
        cb[HID + c] = w1 * sc;
        cb[2 * HID + c] = w2 * sc;
        cb[3 * HID + c] = bb[c] * sc + (beta[c] - mean * sc);
    }
    __syncthreads();
    float a = prelu[0];
    int stride = gridDim.x * blockDim.x;
    for (int t = blockIdx.x * blockDim.x + tid; t < N_NODES * HID; t += stride) {
        int n = t >> 5, c = t & 31;
        float4 s = S4[n];
        float y = s.w * (s.x * cb[c] + s.y * cb[HID + c] + s.z * cb[2 * HID + c])
                + cb[3 * HID + c];
        out[t] = y >= 0.f ? y : a * y;
    }
}

// ============================ fallback (round-4) path ============================

__global__ void fb_count_kernel(const int* __restrict__ dst, int* __restrict__ cnt) {
    int e = blockIdx.x * blockDim.x + threadIdx.x;
    if (e < N_EDGES) atomicAdd(&cnt[dst[e]], 1);
}

__global__ void fb_xd_kernel(const float* __restrict__ x, const int* __restrict__ cnt,
                             float4* __restrict__ xd, float4* __restrict__ S4) {
    int n = blockIdx.x * blockDim.x + threadIdx.x;
    if (n >= N_NODES) return;
    float rd = rsqrtf(1.0f + (float)cnt[n]);
    float4 v = make_float4(x[3 * n] * rd, x[3 * n + 1] * rd, x[3 * n + 2] * rd, rd);
    xd[n] = v;
    S4[n] = v;
}

__global__ void fb_scatter_kernel(const int* __restrict__ src, const int* __restrict__ dst,
                                  const float4* __restrict__ xd, float4* __restrict__ S4) {
    int e = blockIdx.x * blockDim.x + threadIdx.x;
    if (e >= N_EDGES) return;
    int s = src[e], d = dst[e];
    float4 v = xd[s];
    float* p = (float*)&S4[d];
    atomicAdd(p + 0, v.x);
    atomicAdd(p + 1, v.y);
    atomicAdd(p + 2, v.z);
}

__global__ void fb_stats_kernel(const float4* __restrict__ S4, float* __restrict__ stats) {
    __shared__ float ls[4][9];
    int tid = threadIdx.x;
    int n = blockIdx.x * blockDim.x + tid;
    float st[9];
#pragma unroll
    for (int q = 0; q < 9; ++q) st[q] = 0.f;
    if (n < N_NODES) {
        float4 s = S4[n];
        float ax = s.w * s.x, ay = s.w * s.y, az = s.w * s.z;
        st[0] = ax; st[1] = ay; st[2] = az;
        st[3] = ax * ax; st[4] = ax * ay; st[5] = ax * az;
        st[6] = ay * ay; st[7] = ay * az; st[8] = az * az;
    }
    for (int m = 1; m < 64; m <<= 1)
#pragma unroll
        for (int q = 0; q < 9; ++q) st[q] += __shfl_xor(st[q], m);
    int wv = tid >> 6;
    if ((tid & 63) == 0)
#pragma unroll
        for (int q = 0; q < 9; ++q) ls[wv][q] = st[q];
    __syncthreads();
    if (tid < 9) {
        float s = ls[0][tid] + ls[1][tid] + ls[2][tid] + ls[3][tid];
        atomicAdd(&stats[tid], s);
    }
}

// ============================ launch ============================

extern "C" void kernel_launch(void* const* d_in, const int* in_sizes, int n_in,
                              void* d_out, int out_size, void* d_ws, size_t ws_size,
                              hipStream_t stream) {
    const float* x     = (const float*)d_in[0];
    const int*   ei    = (const int*)d_in[1];   // [2, E]: src row then dst row
    const float* W     = (const float*)d_in[2];
    const float* b     = (const float*)d_in[3];
    const float* gamma = (const float*)d_in[4];
    const float* beta  = (const float*)d_in[5];
    const float* prelu = (const float*)d_in[6];

    const int* src = ei;
    const int* dst = ei + N_EDGES;
    char* ws = (char*)d_ws;
    float* out = (float*)d_out;

    // ---- ws layout (main path), total 16,927,456 B ----
    // stats  @ 0          float[16]           (64)
    // tot    @ 64         int[196]            (784)  -> 848
    // bstart @ 848        int[197]            (788)  -> 1636, pad -> 1664
    // blen   @ 1664       int[NBUCK*NBLK]     (306,544) -> 308,208
    // boffs  @ 308,208    int[NBUCK*NBLK]     (306,544) -> 614,752
    // runoff @ 614,752    int[NBUCK*NBLK]     (306,544) -> 921,296, pad -> 921,312
    // staged @ 921,312    u32[NBLK*EPB]       (6,406,144) -> 7,327,456
    // bbuf2  @ 7,327,456  u32[N_EDGES]        (6,400,000) -> 13,727,456
    // xd     @ 13,727,456 float4[100000]      (1,600,000) -> 15,327,456
    // S4     @ 15,327,456 float4[100000]      (1,600,000) -> 16,927,456
    const size_t NEEDED = 16927456;

    if (ws_size >= NEEDED) {
        float*    stats  = (float*)(ws);
        int*      tot    = (int*)(ws + 64);
        int*      bstart = (int*)(ws + 848);
        int*      blen   = (int*)(ws + 1664);
        int*      boffs  = (int*)(ws + 308208);
        int*      runoff = (int*)(ws + 614752);
        unsigned* staged = (unsigned*)(ws + 921312);
        unsigned* bbuf2  = (unsigned*)(ws + 7327456);
        float4*   xd     = (float4*)(ws + 13727456);
        float4*   S4     = (float4*)(ws + 15327456);

        hipMemsetAsync(stats, 0, 64, stream);
        bin_kernel<<<NBLK, 512, 0, stream>>>(src, dst, staged, blen, boffs);
        scan1_kernel<<<NBUCK, 512, 0, stream>>>(blen, runoff, tot);
        scan2_kernel<<<1, 256, 0, stream>>>(tot, bstart);
        scatter2_kernel<<<NBUCK, 1024, 0, stream>>>(staged, blen, boffs, runoff, bstart,
                                                    x, bbuf2, xd);
        accum_kernel<<<NBUCK, 1024, 0, stream>>>(bbuf2, bstart, xd, S4, stats);
        final_out_kernel<<<2048, 256, 0, stream>>>(S4, stats, W, b, gamma, beta, prelu, out);
    } else {
        // fallback: round-4 direct-atomic path (ws need ~3.6 MB)
        int*    cnt   = (int*)(ws);
        float*  stats = (float*)(ws + 400000);
        float4* xd    = (float4*)(ws + 400640);
        float4* S4    = (float4*)(ws + 2000640);

        hipMemsetAsync(ws, 0, 400064, stream);
        fb_count_kernel<<<(N_EDGES + 255) / 256, 256, 0, stream>>>(dst, cnt);
        fb_xd_kernel<<<(N_NODES + 255) / 256, 256, 0, stream>>>(x, cnt, xd, S4);
        fb_scatter_kernel<<<(N_EDGES + 255) / 256, 256, 0, stream>>>(src, dst, xd, S4);
        fb_stats_kernel<<<(N_NODES + 255) / 256, 256, 0, stream>>>(S4, stats);
        final_out_kernel<<<2048, 256, 0, stream>>>(S4, stats, W, b, gamma, beta, prelu, out);
    }
}

// Round 8
// 142.005 us; speedup vs baseline: 1.1957x; 1.0389x over previous
//
#include <hip/hip_runtime.h>

#define N_NODES 100000
#define N_EDGES 1600000
#define HID 32
#define BN_EPS 1e-5f

#define BSZ    256                  // dst nodes per bucket
#define NBUCK  391                  // ceil(N_NODES / 256)
#define NSLICE 256                  // edge slices
#define EPS    6250                 // edges per slice (256*6250 = 1,600,000 exactly)
#define SRC_MASK 0x1FFFFu

// ============================ main path ============================

// slice-block: LDS histogram of dst-buckets -> cnt[s][b] (coalesced write)
__global__ void count_kernel(const int* __restrict__ dst, int* __restrict__ cnt) {
    __shared__ int hist[NBUCK];
    int tid = threadIdx.x, s = blockIdx.x;
    for (int j = tid; j < NBUCK; j += 1024) hist[j] = 0;
    __syncthreads();
    int e0 = s * EPS, e1 = e0 + EPS;
    if (e1 > N_EDGES) e1 = N_EDGES;
    for (int e = e0 + tid; e < e1; e += 1024)
        atomicAdd(&hist[dst[e] >> 8], 1);
    __syncthreads();
    for (int j = tid; j < NBUCK; j += 1024) cnt[s * NBUCK + j] = hist[j];
}

// bucket-block: exclusive scan over the 256 slices -> runoff[s][b], tot[b]
__global__ void scan1_kernel(const int* __restrict__ cnt, int* __restrict__ runoff,
                             int* __restrict__ tot) {
    __shared__ int sc[NSLICE];
    int t = threadIdx.x, b = blockIdx.x;
    int v = cnt[t * NBUCK + b];
    sc[t] = v;
    __syncthreads();
    for (int off = 1; off < NSLICE; off <<= 1) {
        int u = (t >= off) ? sc[t - off] : 0;
        __syncthreads();
        sc[t] += u;
        __syncthreads();
    }
    runoff[t * NBUCK + b] = sc[t] - v;
    if (t == NSLICE - 1) tot[b] = sc[t];
}

// single block: scan 391 bucket totals -> bstart; also zero stats
__global__ void scan2_kernel(const int* __restrict__ tot, int* __restrict__ bstart,
                             float* __restrict__ stats) {
    __shared__ int sc[512];
    int t = threadIdx.x;
    int v = (t < NBUCK) ? tot[t] : 0;
    sc[t] = v;
    __syncthreads();
    for (int off = 1; off < 512; off <<= 1) {
        int u = (t >= off) ? sc[t - off] : 0;
        __syncthreads();
        sc[t] += u;
        __syncthreads();
    }
    if (t < NBUCK) bstart[t] = sc[t] - v;
    if (t == 0) bstart[NBUCK] = N_EDGES;
    if (t < 16) stats[t] = 0.f;
}

// slice-block: re-read edges, rank via LDS cursors, write packed edge directly
// to its bucket-contiguous position. Bucket regions are block-cooperative but
// run-exclusive; L2 assembles full lines. No global atomics.
__global__ void place_kernel(const int* __restrict__ src, const int* __restrict__ dst,
                             const int* __restrict__ runoff, const int* __restrict__ bstart,
                             unsigned* __restrict__ bbuf2) {
    __shared__ int curs[NBUCK];
    int tid = threadIdx.x, s = blockIdx.x;
    for (int j = tid; j < NBUCK; j += 1024)
        curs[j] = bstart[j] + runoff[s * NBUCK + j];
    __syncthreads();
    int e0 = s * EPS, e1 = e0 + EPS;
    if (e1 > N_EDGES) e1 = N_EDGES;
    for (int e = e0 + tid; e < e1; e += 1024) {
        int d = dst[e];
        int b = d >> 8;
        int p = atomicAdd(&curs[b], 1);
        bbuf2[p] = ((unsigned)(d & 255) << 17) | (unsigned)src[e];
    }
}

// bucket-block: coalesced edge read, LDS degree hist, plain-store xd
__global__ void degxd_kernel(const unsigned* __restrict__ bbuf2, const int* __restrict__ bstart,
                             const float* __restrict__ x, float4* __restrict__ xd) {
    __shared__ int hist[BSZ];
    int tid = threadIdx.x, b = blockIdx.x;
    for (int j = tid; j < BSZ; j += 512) hist[j] = 0;
    __syncthreads();
    int e0 = bstart[b], e1 = bstart[b + 1];
    for (int e = e0 + tid; e < e1; e += 512)
        atomicAdd(&hist[bbuf2[e] >> 17], 1);
    __syncthreads();
    if (tid < BSZ) {
        int n = (b << 8) + tid;
        if (n < N_NODES) {
            float rd = rsqrtf(1.0f + (float)hist[tid]);
            xd[n] = make_float4(x[3 * n] * rd, x[3 * n + 1] * rd, x[3 * n + 2] * rd, rd);
        }
    }
}

// bucket-block: coalesced edge read, xd[src] gathers (L2-resident), LDS S accumulate,
// plain S4 store (self term included), fused 9-scalar BN stats (9 atomics/block)
__global__ void accum_kernel(const unsigned* __restrict__ bbuf2, const int* __restrict__ bstart,
                             const float4* __restrict__ xd, float4* __restrict__ S4,
                             float* __restrict__ stats) {
    __shared__ float S[BSZ * 3];
    __shared__ float ls[8][9];
    int tid = threadIdx.x, b = blockIdx.x;
    for (int j = tid; j < BSZ * 3; j += 512) S[j] = 0.f;
    __syncthreads();
    int e0 = bstart[b], e1 = bstart[b + 1];
    for (int e = e0 + tid; e < e1; e += 512) {
        unsigned p = bbuf2[e];
        float4 v = xd[p & SRC_MASK];
        int l3 = (int)(p >> 17) * 3;
        atomicAdd(&S[l3 + 0], v.x);
        atomicAdd(&S[l3 + 1], v.y);
        atomicAdd(&S[l3 + 2], v.z);
    }
    __syncthreads();
    float st[9];
#pragma unroll
    for (int q = 0; q < 9; ++q) st[q] = 0.f;
    if (tid < BSZ) {
        int n = (b << 8) + tid;
        if (n < N_NODES) {
            float4 self = xd[n];
            float sx = S[tid * 3 + 0] + self.x;
            float sy = S[tid * 3 + 1] + self.y;
            float sz = S[tid * 3 + 2] + self.z;
            S4[n] = make_float4(sx, sy, sz, self.w);   // plain coalesced store
            float ax = self.w * sx, ay = self.w * sy, az = self.w * sz;
            st[0] = ax; st[1] = ay; st[2] = az;
            st[3] = ax * ax; st[4] = ax * ay; st[5] = ax * az;
            st[6] = ay * ay; st[7] = ay * az; st[8] = az * az;
        }
    }
    for (int m = 1; m < 64; m <<= 1)
#pragma unroll
        for (int q = 0; q < 9; ++q) st[q] += __shfl_xor(st[q], m);
    int wv = tid >> 6;
    if ((tid & 63) == 0)
#pragma unroll
        for (int q = 0; q < 9; ++q) ls[wv][q] = st[q];
    __syncthreads();
    if (tid < 9) {
        float s = 0.f;
#pragma unroll
        for (int w = 0; w < 8; ++w) s += ls[w][tid];
        atomicAdd(&stats[tid], s);
    }
}

// fused BN-fold + streaming output
__global__ void final_out_kernel(const float4* __restrict__ S4, const float* __restrict__ stats,
                                 const float* __restrict__ W, const float* __restrict__ bb,
                                 const float* __restrict__ gamma, const float* __restrict__ beta,
                                 const float* __restrict__ prelu, float* __restrict__ out) {
    __shared__ float cb[4 * HID];
    int tid = threadIdx.x;
    if (tid < HID) {
        int c = tid;
        float m1x = stats[0], m1y = stats[1], m1z = stats[2];
        float Mxx = stats[3], Mxy = stats[4], Mxz = stats[5];
        float Myy = stats[6], Myz = stats[7], Mzz = stats[8];
        float w0 = W[c], w1 = W[HID + c], w2 = W[2 * HID + c];
        const float invn = 1.0f / (float)N_NODES;
        float m1w = m1x * w0 + m1y * w1 + m1z * w2;
        float mean = m1w * invn + bb[c];
        float quad = w0 * w0 * Mxx + w1 * w1 * Myy + w2 * w2 * Mzz
                   + 2.f * (w0 * w1 * Mxy + w0 * w2 * Mxz + w1 * w2 * Myz);
        float ex2 = quad * invn + 2.f * bb[c] * m1w * invn + bb[c] * bb[c];
        float var = ex2 - mean * mean;
        float sc = gamma[c] * rsqrtf(var + BN_EPS);
        cb[c] = w0 * sc;
        cb[HID + c] = w1 * sc;
        cb[2 * HID + c] = w2 * sc;
        cb[3 * HID + c] = bb[c] * sc + (beta[c] - mean * sc);
    }
    __syncthreads();
    float a = prelu[0];
    int stride = gridDim.x * blockDim.x;
    for (int t = blockIdx.x * blockDim.x + tid; t < N_NODES * HID; t += stride) {
        int n = t >> 5, c = t & 31;
        float4 s = S4[n];
        float y = s.w * (s.x * cb[c] + s.y * cb[HID + c] + s.z * cb[2 * HID + c])
                + cb[3 * HID + c];
        out[t] = y >= 0.f ? y : a * y;
    }
}

// ============================ fallback (round-4) path ============================

__global__ void fb_count_kernel(const int* __restrict__ dst, int* __restrict__ cnt) {
    int e = blockIdx.x * blockDim.x + threadIdx.x;
    if (e < N_EDGES) atomicAdd(&cnt[dst[e]], 1);
}

__global__ void fb_xd_kernel(const float* __restrict__ x, const int* __restrict__ cnt,
                             float4* __restrict__ xd, float4* __restrict__ S4) {
    int n = blockIdx.x * blockDim.x + threadIdx.x;
    if (n >= N_NODES) return;
    float rd = rsqrtf(1.0f + (float)cnt[n]);
    float4 v = make_float4(x[3 * n] * rd, x[3 * n + 1] * rd, x[3 * n + 2] * rd, rd);
    xd[n] = v;
    S4[n] = v;
}

__global__ void fb_scatter_kernel(const int* __restrict__ src, const int* __restrict__ dst,
                                  const float4* __restrict__ xd, float4* __restrict__ S4) {
    int e = blockIdx.x * blockDim.x + threadIdx.x;
    if (e >= N_EDGES) return;
    int s = src[e], d = dst[e];
    float4 v = xd[s];
    float* p = (float*)&S4[d];
    atomicAdd(p + 0, v.x);
    atomicAdd(p + 1, v.y);
    atomicAdd(p + 2, v.z);
}

__global__ void fb_stats_kernel(const float4* __restrict__ S4, float* __restrict__ stats) {
    __shared__ float ls[4][9];
    int tid = threadIdx.x;
    int n = blockIdx.x * blockDim.x + tid;
    float st[9];
#pragma unroll
    for (int q = 0; q < 9; ++q) st[q] = 0.f;
    if (n < N_NODES) {
        float4 s = S4[n];
        float ax = s.w * s.x, ay = s.w * s.y, az = s.w * s.z;
        st[0] = ax; st[1] = ay; st[2] = az;
        st[3] = ax * ax; st[4] = ax * ay; st[5] = ax * az;
        st[6] = ay * ay; st[7] = ay * az; st[8] = az * az;
    }
    for (int m = 1; m < 64; m <<= 1)
#pragma unroll
        for (int q = 0; q < 9; ++q) st[q] += __shfl_xor(st[q], m);
    int wv = tid >> 6;
    if ((tid & 63) == 0)
#pragma unroll
        for (int q = 0; q < 9; ++q) ls[wv][q] = st[q];
    __syncthreads();
    if (tid < 9) {
        float s = ls[0][tid] + ls[1][tid] + ls[2][tid] + ls[3][tid];
        atomicAdd(&stats[tid], s);
    }
}

// ============================ launch ============================

extern "C" void kernel_launch(void* const* d_in, const int* in_sizes, int n_in,
                              void* d_out, int out_size, void* d_ws, size_t ws_size,
                              hipStream_t stream) {
    const float* x     = (const float*)d_in[0];
    const int*   ei    = (const int*)d_in[1];   // [2, E]: src row then dst row
    const float* W     = (const float*)d_in[2];
    const float* b     = (const float*)d_in[3];
    const float* gamma = (const float*)d_in[4];
    const float* beta  = (const float*)d_in[5];
    const float* prelu = (const float*)d_in[6];

    const int* src = ei;
    const int* dst = ei + N_EDGES;
    char* ws = (char*)d_ws;
    float* out = (float*)d_out;

    // ---- ws layout (main path), total 10,403,968 B ----
    // stats  @ 0          float[16]            (64)
    // tot    @ 64         int[391]             (1,564) -> pad 1,632
    // bstart @ 1,632      int[392]             (1,568) -> 3,200
    // cnt    @ 3,200      int[NSLICE*NBUCK]    (400,384) -> 403,584
    // runoff @ 403,584    int[NSLICE*NBUCK]    (400,384) -> 803,968
    // bbuf2  @ 803,968    u32[N_EDGES]         (6,400,000) -> 7,203,968
    // xd     @ 7,203,968  float4[100000]       (1,600,000) -> 8,803,968   (16B-aligned)
    // S4     @ 8,803,968  float4[100000]       (1,600,000) -> 10,403,968  (16B-aligned)
    const size_t NEEDED = 10403968;

    if (ws_size >= NEEDED) {
        float*    stats  = (float*)(ws);
        int*      tot    = (int*)(ws + 64);
        int*      bstart = (int*)(ws + 1632);
        int*      cnt    = (int*)(ws + 3200);
        int*      runoff = (int*)(ws + 403584);
        unsigned* bbuf2  = (unsigned*)(ws + 803968);
        float4*   xd     = (float4*)(ws + 7203968);
        float4*   S4     = (float4*)(ws + 8803968);

        count_kernel<<<NSLICE, 1024, 0, stream>>>(dst, cnt);
        scan1_kernel<<<NBUCK, NSLICE, 0, stream>>>(cnt, runoff, tot);
        scan2_kernel<<<1, 512, 0, stream>>>(tot, bstart, stats);
        place_kernel<<<NSLICE, 1024, 0, stream>>>(src, dst, runoff, bstart, bbuf2);
        degxd_kernel<<<NBUCK, 512, 0, stream>>>(bbuf2, bstart, x, xd);
        accum_kernel<<<NBUCK, 512, 0, stream>>>(bbuf2, bstart, xd, S4, stats);
        final_out_kernel<<<2048, 256, 0, stream>>>(S4, stats, W, b, gamma, beta, prelu, out);
    } else {
        // fallback: round-4 direct-atomic path (ws need ~3.6 MB)
        int*    cnt   = (int*)(ws);
        float*  stats = (float*)(ws + 400000);
        float4* xd    = (float4*)(ws + 400640);
        float4* S4    = (float4*)(ws + 2000640);

        hipMemsetAsync(ws, 0, 400064, stream);
        fb_count_kernel<<<(N_EDGES + 255) / 256, 256, 0, stream>>>(dst, cnt);
        fb_xd_kernel<<<(N_NODES + 255) / 256, 256, 0, stream>>>(x, cnt, xd, S4);
        fb_scatter_kernel<<<(N_EDGES + 255) / 256, 256, 0, stream>>>(src, dst, xd, S4);
        fb_stats_kernel<<<(N_NODES + 255) / 256, 256, 0, stream>>>(S4, stats);
        final_out_kernel<<<2048, 256, 0, stream>>>(S4, stats, W, b, gamma, beta, prelu, out);
    }
}